// Round 1
// baseline (522.547 us; speedup 1.0000x reference)
//
#include <hip/hip_runtime.h>
#include <hip/hip_bf16.h>
#include <stdint.h>

// Problem dims (fixed by reference): B=4096, I=2048, H=2048, K=I+H=4096
#define BB 4096
#define II 2048
#define HH 2048
#define KK 4096

typedef __bf16 bf16x8 __attribute__((ext_vector_type(8)));
typedef float f32x4 __attribute__((ext_vector_type(4)));

typedef __attribute__((address_space(3))) uint32_t lds_u32;
typedef const __attribute__((address_space(1))) uint32_t glb_u32;

__device__ __forceinline__ void load_lds16(const void* g, void* l) {
    __builtin_amdgcn_global_load_lds((glb_u32*)g, (lds_u32*)l, 16, 0, 0);
}

// ---------------------------------------------------------------------------
// prep_weights: sign(w) -> bf16 (+-1.0 / 0.0), and sum |w| -> scales[which]
// grid: (512, 3), block 256.  each tensor is 2048*4096 = 8,388,608 f32.
// ---------------------------------------------------------------------------
__global__ __launch_bounds__(256) void prep_weights(
    const float* __restrict__ w_r, const float* __restrict__ w_z,
    const float* __restrict__ w_n,
    __hip_bfloat16* __restrict__ sign_rz, __hip_bfloat16* __restrict__ sign_n,
    float* __restrict__ scales)
{
    const int which = blockIdx.y;
    const float* w = (which == 0) ? w_r : (which == 1 ? w_z : w_n);
    __hip_bfloat16* dst = (which == 0) ? sign_rz
                        : (which == 1 ? sign_rz + (size_t)HH * KK : sign_n);

    const int total4 = HH * KK / 4;            // 2,097,152 float4s
    const int tid = blockIdx.x * 256 + threadIdx.x;
    const int stride = gridDim.x * 256;

    float s = 0.0f;
    for (int i = tid; i < total4; i += stride) {
        float4 v = reinterpret_cast<const float4*>(w)[i];
        s += fabsf(v.x) + fabsf(v.y) + fabsf(v.z) + fabsf(v.w);
        ushort4 o;
        o.x = (v.x == 0.0f) ? 0 : (ushort)(0x3F80u | ((__float_as_uint(v.x) >> 16) & 0x8000u));
        o.y = (v.y == 0.0f) ? 0 : (ushort)(0x3F80u | ((__float_as_uint(v.y) >> 16) & 0x8000u));
        o.z = (v.z == 0.0f) ? 0 : (ushort)(0x3F80u | ((__float_as_uint(v.z) >> 16) & 0x8000u));
        o.w = (v.w == 0.0f) ? 0 : (ushort)(0x3F80u | ((__float_as_uint(v.w) >> 16) & 0x8000u));
        *reinterpret_cast<ushort4*>(&dst[(size_t)i * 4]) = o;
    }

    // block reduce (4 waves)
    #pragma unroll
    for (int o = 32; o > 0; o >>= 1) s += __shfl_xor(s, o);
    __shared__ float red[4];
    const int wid = threadIdx.x >> 6, lane = threadIdx.x & 63;
    if (lane == 0) red[wid] = s;
    __syncthreads();
    if (threadIdx.x == 0)
        atomicAdd(&scales[which], red[0] + red[1] + red[2] + red[3]);
}

// ---------------------------------------------------------------------------
// prep_inputs: x -> bf16 into combined[:,0:2048] and combined2[:,0:2048];
//              hidden -> bf16 into combined[:,2048:4096]
// grid: (1024, 2), block 256.  each tensor 4096*2048 f32.
// ---------------------------------------------------------------------------
__global__ __launch_bounds__(256) void prep_inputs(
    const float* __restrict__ x, const float* __restrict__ hidden,
    __hip_bfloat16* __restrict__ combined, __hip_bfloat16* __restrict__ combined2)
{
    const int which = blockIdx.y;            // 0: x, 1: hidden
    const float* src = which ? hidden : x;
    const int total4 = BB * II / 4;          // 2,097,152
    const int tid = blockIdx.x * 256 + threadIdx.x;
    const int stride = gridDim.x * 256;

    for (int i = tid; i < total4; i += stride) {
        float4 v = reinterpret_cast<const float4*>(src)[i];
        int e = i * 4;
        int row = e >> 11;                   // /2048
        int col = e & 2047;
        union { ushort4 u; __hip_bfloat16 h[4]; } o;
        o.h[0] = __float2bfloat16(v.x);
        o.h[1] = __float2bfloat16(v.y);
        o.h[2] = __float2bfloat16(v.z);
        o.h[3] = __float2bfloat16(v.w);
        size_t off = (size_t)row * KK + (which ? 2048 + col : col);
        *reinterpret_cast<ushort4*>(&combined[off]) = o.u;
        if (!which)
            *reinterpret_cast<ushort4*>(&combined2[off]) = o.u;
    }
}

// ---------------------------------------------------------------------------
// gemm: C = A[M,K] @ W[N,K]^T  with binarized-weight epilogues.
// 128x128 tile, BK=32, 256 threads (4 waves, 2x2), 4x4 16x16x32 mfma / wave.
// EPI==1: N=4096 (r||z).  bn<16 -> r: combined2[:,2048+j]=bf16(sig*hidden)
//                         bn>=16 -> z_buf = sigmoid (fp32)
// EPI==2: N=2048 (n).  out = (1-z)*hidden + z*tanh(...)
// ---------------------------------------------------------------------------
template <int EPI>
__global__ __launch_bounds__(256) void gemm_bin(
    const __hip_bfloat16* __restrict__ A,    // [4096][4096] bf16
    const __hip_bfloat16* __restrict__ Bw,   // [N][4096] bf16 (signs)
    const float* __restrict__ scales,        // [3] sum|w|
    const float* __restrict__ b_r, const float* __restrict__ b_z,
    const float* __restrict__ b_n,
    const float* __restrict__ hidden,        // [4096][2048] f32
    float* __restrict__ z_buf,               // [4096][2048] f32
    __hip_bfloat16* __restrict__ combined2,  // [4096][4096] bf16
    float* __restrict__ out)                 // [4096][2048] f32
{
    __shared__ __align__(16) __hip_bfloat16 lA[128 * 32];
    __shared__ __align__(16) __hip_bfloat16 lB[128 * 32];

    const int t = threadIdx.x;
    const int bn = blockIdx.x, bm = blockIdx.y;
    const int wid = t >> 6, lane = t & 63;
    const int wr = wid >> 1, wc = wid & 1;

    f32x4 acc[4][4] = {};

    // staging addresses: thread t loads 16B (8 bf16) of row t/4, cols (t&3)*8
    const __hip_bfloat16* gA0 = A  + (size_t)(bm * 128 + (t >> 2)) * KK + (t & 3) * 8;
    const __hip_bfloat16* gB0 = Bw + (size_t)(bn * 128 + (t >> 2)) * KK + (t & 3) * 8;
    const __hip_bfloat16* gA1 = gA0 + (size_t)64 * KK;
    const __hip_bfloat16* gB1 = gB0 + (size_t)64 * KK;
    __hip_bfloat16* lA0 = &lA[t * 8];
    __hip_bfloat16* lA1 = &lA[2048 + t * 8];
    __hip_bfloat16* lB0 = &lB[t * 8];
    __hip_bfloat16* lB1 = &lB[2048 + t * 8];

    const int arow[4] = { (wr * 64 + 0 * 16 + (lane & 15)) * 32,
                          (wr * 64 + 1 * 16 + (lane & 15)) * 32,
                          (wr * 64 + 2 * 16 + (lane & 15)) * 32,
                          (wr * 64 + 3 * 16 + (lane & 15)) * 32 };
    const int brow[4] = { (wc * 64 + 0 * 16 + (lane & 15)) * 32,
                          (wc * 64 + 1 * 16 + (lane & 15)) * 32,
                          (wc * 64 + 2 * 16 + (lane & 15)) * 32,
                          (wc * 64 + 3 * 16 + (lane & 15)) * 32 };
    const int koff = (lane >> 4) * 8;

    for (int k0 = 0; k0 < KK; k0 += 32) {
        __syncthreads();
        load_lds16(gA0 + k0, lA0);
        load_lds16(gA1 + k0, lA1);
        load_lds16(gB0 + k0, lB0);
        load_lds16(gB1 + k0, lB1);
        __syncthreads();   // compiler drains vmcnt before s_barrier

        bf16x8 af[4], bfr[4];
        #pragma unroll
        for (int m = 0; m < 4; m++)
            af[m] = *reinterpret_cast<const bf16x8*>(&lA[arow[m] + koff]);
        #pragma unroll
        for (int n = 0; n < 4; n++)
            bfr[n] = *reinterpret_cast<const bf16x8*>(&lB[brow[n] + koff]);
        #pragma unroll
        for (int m = 0; m < 4; m++)
            #pragma unroll
            for (int n = 0; n < 4; n++)
                acc[m][n] = __builtin_amdgcn_mfma_f32_16x16x32_bf16(
                    af[m], bfr[n], acc[m][n], 0, 0, 0);
    }

    const float inv_cnt = 1.0f / ((float)HH * (float)KK);

    if (EPI == 1) {
        const bool is_r = (bn < 16);
        const float scale = (is_r ? scales[0] : scales[1]) * inv_cnt;
        const float* bias = is_r ? b_r : b_z;
        #pragma unroll
        for (int m = 0; m < 4; m++) {
            #pragma unroll
            for (int n = 0; n < 4; n++) {
                int col = bn * 128 + wc * 64 + n * 16 + (lane & 15);
                int j = is_r ? col : col - 2048;
                float bj = bias[j];
                #pragma unroll
                for (int i = 0; i < 4; i++) {
                    int row = bm * 128 + wr * 64 + m * 16 + (lane >> 4) * 4 + i;
                    float pre = acc[m][n][i] * scale + bj;
                    float sg = 1.0f / (1.0f + __expf(-pre));
                    if (is_r) {
                        float rh = sg * hidden[(size_t)row * HH + j];
                        combined2[(size_t)row * KK + 2048 + j] = __float2bfloat16(rh);
                    } else {
                        z_buf[(size_t)row * HH + j] = sg;
                    }
                }
            }
        }
    } else {
        const float scale = scales[2] * inv_cnt;
        #pragma unroll
        for (int m = 0; m < 4; m++) {
            #pragma unroll
            for (int n = 0; n < 4; n++) {
                int col = bn * 128 + wc * 64 + n * 16 + (lane & 15);
                float bj = b_n[col];
                #pragma unroll
                for (int i = 0; i < 4; i++) {
                    int row = bm * 128 + wr * 64 + m * 16 + (lane >> 4) * 4 + i;
                    float pre = acc[m][n][i] * scale + bj;
                    float nn = tanhf(pre);
                    size_t o = (size_t)row * HH + col;
                    float z = z_buf[o];
                    float h = hidden[o];
                    out[o] = (1.0f - z) * h + z * nn;
                }
            }
        }
    }
}

// ---------------------------------------------------------------------------
extern "C" void kernel_launch(void* const* d_in, const int* in_sizes, int n_in,
                              void* d_out, int out_size, void* d_ws, size_t ws_size,
                              hipStream_t stream) {
    const float* x      = (const float*)d_in[0];
    const float* hidden = (const float*)d_in[1];
    const float* w_r    = (const float*)d_in[2];
    const float* b_r    = (const float*)d_in[3];
    const float* w_z    = (const float*)d_in[4];
    const float* b_z    = (const float*)d_in[5];
    const float* w_n    = (const float*)d_in[6];
    const float* b_n    = (const float*)d_in[7];
    float* out = (float*)d_out;

    char* ws = (char*)d_ws;
    size_t off = 0;
    float* scales = (float*)(ws + off);                 off += 256;
    __hip_bfloat16* combined  = (__hip_bfloat16*)(ws + off); off += (size_t)BB * KK * 2;
    __hip_bfloat16* combined2 = (__hip_bfloat16*)(ws + off); off += (size_t)BB * KK * 2;
    __hip_bfloat16* sign_rz   = (__hip_bfloat16*)(ws + off); off += (size_t)2 * HH * KK * 2;
    __hip_bfloat16* sign_n    = (__hip_bfloat16*)(ws + off); off += (size_t)HH * KK * 2;
    float* z_buf = (float*)(ws + off);                  off += (size_t)BB * HH * 4;

    hipMemsetAsync(scales, 0, 3 * sizeof(float), stream);

    prep_weights<<<dim3(512, 3), 256, 0, stream>>>(w_r, w_z, w_n,
                                                   sign_rz, sign_n, scales);
    prep_inputs<<<dim3(1024, 2), 256, 0, stream>>>(x, hidden, combined, combined2);

    // GEMM1: r||z  (N = 4096)
    gemm_bin<1><<<dim3(32, 32), 256, 0, stream>>>(combined, sign_rz, scales,
                                                  b_r, b_z, b_n, hidden,
                                                  z_buf, combined2, out);
    // GEMM2: n  (N = 2048)
    gemm_bin<2><<<dim3(16, 32), 256, 0, stream>>>(combined2, sign_n, scales,
                                                  b_r, b_z, b_n, hidden,
                                                  z_buf, combined2, out);
}

// Round 2
// 486.747 us; speedup vs baseline: 1.0735x; 1.0735x over previous
//
#include <hip/hip_runtime.h>
#include <hip/hip_bf16.h>
#include <stdint.h>

// Problem dims (fixed by reference): B=4096, I=2048, H=2048, K=I+H=4096
#define BB 4096
#define II 2048
#define HH 2048
#define KK 4096
#define NT 64   // K tiles of 64

typedef __bf16 bf16x8 __attribute__((ext_vector_type(8)));
typedef float f32x4 __attribute__((ext_vector_type(4)));

typedef __attribute__((address_space(3))) uint32_t lds_u32;
typedef const __attribute__((address_space(1))) uint32_t glb_u32;

__device__ __forceinline__ void load_lds16(const void* g, void* l) {
    __builtin_amdgcn_global_load_lds((glb_u32*)g, (lds_u32*)l, 16, 0, 0);
}

// ---------------------------------------------------------------------------
// prep_weights: sign(w) -> bf16 (+-1.0 / 0.0), and sum |w| -> scales[which]
// ---------------------------------------------------------------------------
__global__ __launch_bounds__(256) void prep_weights(
    const float* __restrict__ w_r, const float* __restrict__ w_z,
    const float* __restrict__ w_n,
    __hip_bfloat16* __restrict__ sign_rz, __hip_bfloat16* __restrict__ sign_n,
    float* __restrict__ scales)
{
    const int which = blockIdx.y;
    const float* w = (which == 0) ? w_r : (which == 1 ? w_z : w_n);
    __hip_bfloat16* dst = (which == 0) ? sign_rz
                        : (which == 1 ? sign_rz + (size_t)HH * KK : sign_n);

    const int total4 = HH * KK / 4;
    const int tid = blockIdx.x * 256 + threadIdx.x;
    const int stride = gridDim.x * 256;

    float s = 0.0f;
    for (int i = tid; i < total4; i += stride) {
        float4 v = reinterpret_cast<const float4*>(w)[i];
        s += fabsf(v.x) + fabsf(v.y) + fabsf(v.z) + fabsf(v.w);
        ushort4 o;
        o.x = (v.x == 0.0f) ? 0 : (ushort)(0x3F80u | ((__float_as_uint(v.x) >> 16) & 0x8000u));
        o.y = (v.y == 0.0f) ? 0 : (ushort)(0x3F80u | ((__float_as_uint(v.y) >> 16) & 0x8000u));
        o.z = (v.z == 0.0f) ? 0 : (ushort)(0x3F80u | ((__float_as_uint(v.z) >> 16) & 0x8000u));
        o.w = (v.w == 0.0f) ? 0 : (ushort)(0x3F80u | ((__float_as_uint(v.w) >> 16) & 0x8000u));
        *reinterpret_cast<ushort4*>(&dst[(size_t)i * 4]) = o;
    }

    #pragma unroll
    for (int o = 32; o > 0; o >>= 1) s += __shfl_xor(s, o);
    __shared__ float red[4];
    const int wid = threadIdx.x >> 6, lane = threadIdx.x & 63;
    if (lane == 0) red[wid] = s;
    __syncthreads();
    if (threadIdx.x == 0)
        atomicAdd(&scales[which], red[0] + red[1] + red[2] + red[3]);
}

// ---------------------------------------------------------------------------
// prep_inputs: x -> bf16 into combined[:,0:2048] and combined2[:,0:2048];
//              hidden -> bf16 into combined[:,2048:4096]
// ---------------------------------------------------------------------------
__global__ __launch_bounds__(256) void prep_inputs(
    const float* __restrict__ x, const float* __restrict__ hidden,
    __hip_bfloat16* __restrict__ combined, __hip_bfloat16* __restrict__ combined2)
{
    const int which = blockIdx.y;
    const float* src = which ? hidden : x;
    const int total4 = BB * II / 4;
    const int tid = blockIdx.x * 256 + threadIdx.x;
    const int stride = gridDim.x * 256;

    for (int i = tid; i < total4; i += stride) {
        float4 v = reinterpret_cast<const float4*>(src)[i];
        int e = i * 4;
        int row = e >> 11;
        int col = e & 2047;
        union { ushort4 u; __hip_bfloat16 h[4]; } o;
        o.h[0] = __float2bfloat16(v.x);
        o.h[1] = __float2bfloat16(v.y);
        o.h[2] = __float2bfloat16(v.z);
        o.h[3] = __float2bfloat16(v.w);
        size_t off = (size_t)row * KK + (which ? 2048 + col : col);
        *reinterpret_cast<ushort4*>(&combined[off]) = o.u;
        if (!which)
            *reinterpret_cast<ushort4*>(&combined2[off]) = o.u;
    }
}

// ---------------------------------------------------------------------------
// 256x256 8-phase GEMM (m201-style): C = A[M,K] @ W[N,K]^T, binarized epilogues
// 512 threads = 8 waves (2M x 4N), per-wave 128x64 out, BK=64, dbuf LDS 128KB.
// Per K-tile: 4 phases x {ds_read subtile | stage 1 half-tile | barrier |
//   lgkmcnt(0) | setprio(1) 16xMFMA setprio(0) | barrier}; vmcnt(4) at phase 3.
// LDS swizzle: byte ^= (row&7)<<4, applied on global SOURCE (staging) and
// ds_read address; global_load_lds dest stays linear (rule #21).
// ---------------------------------------------------------------------------
#define PH_MFMA(m0)                                                            \
    _Pragma("unroll") for (int mm = 0; mm < 2; mm++)                           \
    _Pragma("unroll") for (int n = 0; n < 4; n++)                              \
    _Pragma("unroll") for (int k = 0; k < 2; k++)                              \
        acc[(m0) + mm][n] = __builtin_amdgcn_mfma_f32_16x16x32_bf16(           \
            afr[mm][k], bfrag[n][k], acc[(m0) + mm][n], 0, 0, 0);

#define PH_SYNC_PRE()                                                          \
    __builtin_amdgcn_s_barrier();                                              \
    asm volatile("s_waitcnt lgkmcnt(0)" ::: "memory");                         \
    __builtin_amdgcn_sched_barrier(0);                                         \
    __builtin_amdgcn_s_setprio(1);

#define PH_SYNC_POST()                                                         \
    __builtin_amdgcn_s_setprio(0);                                             \
    __builtin_amdgcn_s_barrier();

template <int EPI>
__global__ __launch_bounds__(512, 2) void gemm8p(
    const __hip_bfloat16* __restrict__ A,    // [4096][4096] bf16
    const __hip_bfloat16* __restrict__ Bw,   // [N][4096] bf16 (signs)
    const float* __restrict__ scales,
    const float* __restrict__ b_r, const float* __restrict__ b_z,
    const float* __restrict__ b_n,
    const float* __restrict__ hidden,        // [4096][2048] f32
    float* __restrict__ z_buf,               // [4096][2048] f32
    __hip_bfloat16* __restrict__ combined2,  // [4096][4096] bf16
    float* __restrict__ out)                 // [4096][2048] f32
{
    __shared__ __align__(16) char smem[131072];  // [A dbuf 64KB][B dbuf 64KB]

    const int T = threadIdx.x;
    const int lane = T & 63;
    const int wid = T >> 6;
    const int wr = wid >> 2;    // 0..1
    const int wc = wid & 3;     // 0..3

    // bijective XCD swizzle (nwg % 8 == 0 for both grids)
    const int nbn = gridDim.x;
    const int nwg = nbn * gridDim.y;
    const int bid = blockIdx.y * nbn + blockIdx.x;
    const int swz = (bid & 7) * (nwg >> 3) + (bid >> 3);
    const int bn = swz % nbn;
    const int bm = swz / nbn;

    // fragment read byte-offsets within a 32KB tile buffer (swizzled)
    int arowb[8], browb[4], colb[2];
    #pragma unroll
    for (int m = 0; m < 8; m++) arowb[m] = (wr * 128 + m * 16 + (lane & 15)) << 7;
    #pragma unroll
    for (int n = 0; n < 4; n++) browb[n] = (wc * 64 + n * 16 + (lane & 15)) << 7;
    #pragma unroll
    for (int k = 0; k < 2; k++)
        colb[k] = (k * 64 + ((lane >> 4) << 4)) ^ ((lane & 7) << 4);

    // staging: thread T covers row (T>>3), source col pre-inverse-swizzled
    const int srow = T >> 3;                       // 0..63
    const int scol = ((T & 7) ^ (srow & 7)) << 3;  // element offset
    const __hip_bfloat16* gA = A  + (size_t)(bm * 256 + srow) * KK + scol;
    const __hip_bfloat16* gB = Bw + (size_t)(bn * 256 + srow) * KK + scol;
    char* lT = smem + T * 16;

    auto stA = [&](int tile, int h) {
        const __hip_bfloat16* g = gA + (size_t)(h * 128) * KK + ((tile & (NT - 1)) << 6);
        char* l = lT + ((tile & 1) << 15) + (h << 14);
        load_lds16(g, l);
        load_lds16(g + (size_t)64 * KK, l + 8192);
    };
    auto stB = [&](int tile, int h) {
        const __hip_bfloat16* g = gB + (size_t)(h * 128) * KK + ((tile & (NT - 1)) << 6);
        char* l = lT + 65536 + ((tile & 1) << 15) + (h << 14);
        load_lds16(g, l);
        load_lds16(g + (size_t)64 * KK, l + 8192);
    };

    f32x4 acc[8][4] = {};

    // prologue: tile0 fully + tile1 B halves; leave newest 2 halves in flight
    stA(0, 0); stA(0, 1); stB(0, 0); stB(0, 1); stB(1, 0); stB(1, 1);
    asm volatile("s_waitcnt vmcnt(4)" ::: "memory");
    __builtin_amdgcn_sched_barrier(0);
    __builtin_amdgcn_s_barrier();

    for (int t = 0; t < NT; ++t) {
        const char* ab = smem + ((t & 1) << 15);
        const char* bb = smem + 65536 + ((t & 1) << 15);

        bf16x8 bfrag[4][2];
        bf16x8 afr[2][2];

        // ---- phase 0: read all B frags + A m=0,1; stage A0(t+1)
        #pragma unroll
        for (int n = 0; n < 4; n++)
            #pragma unroll
            for (int k = 0; k < 2; k++)
                bfrag[n][k] = *(const bf16x8*)(bb + browb[n] + colb[k]);
        #pragma unroll
        for (int mm = 0; mm < 2; mm++)
            #pragma unroll
            for (int k = 0; k < 2; k++)
                afr[mm][k] = *(const bf16x8*)(ab + arowb[mm] + colb[k]);
        stA(t + 1, 0);
        PH_SYNC_PRE();
        PH_MFMA(0);
        PH_SYNC_POST();

        // ---- phase 1: A m=2,3; stage A1(t+1)
        #pragma unroll
        for (int mm = 0; mm < 2; mm++)
            #pragma unroll
            for (int k = 0; k < 2; k++)
                afr[mm][k] = *(const bf16x8*)(ab + arowb[2 + mm] + colb[k]);
        stA(t + 1, 1);
        PH_SYNC_PRE();
        PH_MFMA(2);
        PH_SYNC_POST();

        // ---- phase 2: A m=4,5; stage B0(t+2)
        #pragma unroll
        for (int mm = 0; mm < 2; mm++)
            #pragma unroll
            for (int k = 0; k < 2; k++)
                afr[mm][k] = *(const bf16x8*)(ab + arowb[4 + mm] + colb[k]);
        stB(t + 2, 0);
        PH_SYNC_PRE();
        PH_MFMA(4);
        PH_SYNC_POST();

        // ---- phase 3: A m=6,7; stage B1(t+2); counted vmcnt (never 0)
        #pragma unroll
        for (int mm = 0; mm < 2; mm++)
            #pragma unroll
            for (int k = 0; k < 2; k++)
                afr[mm][k] = *(const bf16x8*)(ab + arowb[6 + mm] + colb[k]);
        stB(t + 2, 1);
        asm volatile("s_waitcnt vmcnt(4)" ::: "memory");
        __builtin_amdgcn_sched_barrier(0);
        PH_SYNC_PRE();
        PH_MFMA(6);
        PH_SYNC_POST();
    }

    asm volatile("s_waitcnt vmcnt(0)" ::: "memory");
    __builtin_amdgcn_sched_barrier(0);

    // ---- epilogue
    const float inv_cnt = 1.0f / ((float)HH * (float)KK);

    if (EPI == 1) {
        const bool is_r = (bn < 8);
        const float scale = (is_r ? scales[0] : scales[1]) * inv_cnt;
        const float* bias = is_r ? b_r : b_z;
        #pragma unroll
        for (int m = 0; m < 8; m++) {
            #pragma unroll
            for (int n = 0; n < 4; n++) {
                const int col = bn * 256 + wc * 64 + n * 16 + (lane & 15);
                const int j = is_r ? col : col - 2048;
                const float bj = bias[j];
                #pragma unroll
                for (int i = 0; i < 4; i++) {
                    const int row = bm * 256 + wr * 128 + m * 16 + ((lane >> 4) << 2) + i;
                    float pre = acc[m][n][i] * scale + bj;
                    float sg = 1.0f / (1.0f + __expf(-pre));
                    if (is_r) {
                        float rh = sg * hidden[(size_t)row * HH + j];
                        combined2[(size_t)row * KK + 2048 + j] = __float2bfloat16(rh);
                    } else {
                        z_buf[(size_t)row * HH + j] = sg;
                    }
                }
            }
        }
    } else {
        const float scale = scales[2] * inv_cnt;
        #pragma unroll
        for (int m = 0; m < 8; m++) {
            #pragma unroll
            for (int n = 0; n < 4; n++) {
                const int col = bn * 256 + wc * 64 + n * 16 + (lane & 15);
                const float bj = b_n[col];
                #pragma unroll
                for (int i = 0; i < 4; i++) {
                    const int row = bm * 256 + wr * 128 + m * 16 + ((lane >> 4) << 2) + i;
                    float pre = acc[m][n][i] * scale + bj;
                    float nn = tanhf(pre);
                    size_t o = (size_t)row * HH + col;
                    float z = z_buf[o];
                    float h = hidden[o];
                    out[o] = (1.0f - z) * h + z * nn;
                }
            }
        }
    }
}

// ---------------------------------------------------------------------------
extern "C" void kernel_launch(void* const* d_in, const int* in_sizes, int n_in,
                              void* d_out, int out_size, void* d_ws, size_t ws_size,
                              hipStream_t stream) {
    const float* x      = (const float*)d_in[0];
    const float* hidden = (const float*)d_in[1];
    const float* w_r    = (const float*)d_in[2];
    const float* b_r    = (const float*)d_in[3];
    const float* w_z    = (const float*)d_in[4];
    const float* b_z    = (const float*)d_in[5];
    const float* w_n    = (const float*)d_in[6];
    const float* b_n    = (const float*)d_in[7];
    float* out = (float*)d_out;

    char* ws = (char*)d_ws;
    size_t off = 0;
    float* scales = (float*)(ws + off);                 off += 256;
    __hip_bfloat16* combined  = (__hip_bfloat16*)(ws + off); off += (size_t)BB * KK * 2;
    __hip_bfloat16* combined2 = (__hip_bfloat16*)(ws + off); off += (size_t)BB * KK * 2;
    __hip_bfloat16* sign_rz   = (__hip_bfloat16*)(ws + off); off += (size_t)2 * HH * KK * 2;
    __hip_bfloat16* sign_n    = (__hip_bfloat16*)(ws + off); off += (size_t)HH * KK * 2;
    float* z_buf = (float*)(ws + off);                  off += (size_t)BB * HH * 4;

    hipMemsetAsync(scales, 0, 3 * sizeof(float), stream);

    prep_weights<<<dim3(512, 3), 256, 0, stream>>>(w_r, w_z, w_n,
                                                   sign_rz, sign_n, scales);
    prep_inputs<<<dim3(1024, 2), 256, 0, stream>>>(x, hidden, combined, combined2);

    // GEMM1: r||z  (N = 4096), 256 blocks = 1/CU
    gemm8p<1><<<dim3(16, 16), 512, 0, stream>>>(combined, sign_rz, scales,
                                                b_r, b_z, b_n, hidden,
                                                z_buf, combined2, out);
    // GEMM2: n  (N = 2048)
    gemm8p<2><<<dim3(8, 16), 512, 0, stream>>>(combined2, sign_n, scales,
                                               b_r, b_z, b_n, hidden,
                                               z_buf, combined2, out);
}

// Round 3
// 418.925 us; speedup vs baseline: 1.2474x; 1.1619x over previous
//
#include <hip/hip_runtime.h>
#include <hip/hip_bf16.h>
#include <stdint.h>

// Problem dims (fixed by reference): B=4096, I=2048, H=2048, K=I+H=4096
#define BB 4096
#define II 2048
#define HH 2048
#define KK 4096
#define NITER 32   // 32 iterations x 2 K-tiles (BK=64) = K 4096

typedef __bf16 bf16x8 __attribute__((ext_vector_type(8)));
typedef float f32x4 __attribute__((ext_vector_type(4)));

typedef __attribute__((address_space(3))) uint32_t lds_u32;
typedef const __attribute__((address_space(1))) uint32_t glb_u32;

__device__ __forceinline__ void load_lds16(const void* g, void* l) {
    __builtin_amdgcn_global_load_lds((glb_u32*)g, (lds_u32*)l, 16, 0, 0);
}

// ---------------------------------------------------------------------------
// prep_weights: sign(w) -> bf16 (+-1.0 / 0.0), and sum |w| -> scales[which]
// ---------------------------------------------------------------------------
__global__ __launch_bounds__(256) void prep_weights(
    const float* __restrict__ w_r, const float* __restrict__ w_z,
    const float* __restrict__ w_n,
    __hip_bfloat16* __restrict__ sign_rz, __hip_bfloat16* __restrict__ sign_n,
    float* __restrict__ scales)
{
    const int which = blockIdx.y;
    const float* w = (which == 0) ? w_r : (which == 1 ? w_z : w_n);
    __hip_bfloat16* dst = (which == 0) ? sign_rz
                        : (which == 1 ? sign_rz + (size_t)HH * KK : sign_n);

    const int total4 = HH * KK / 4;
    const int tid = blockIdx.x * 256 + threadIdx.x;
    const int stride = gridDim.x * 256;

    float s = 0.0f;
    for (int i = tid; i < total4; i += stride) {
        float4 v = reinterpret_cast<const float4*>(w)[i];
        s += fabsf(v.x) + fabsf(v.y) + fabsf(v.z) + fabsf(v.w);
        ushort4 o;
        o.x = (v.x == 0.0f) ? 0 : (ushort)(0x3F80u | ((__float_as_uint(v.x) >> 16) & 0x8000u));
        o.y = (v.y == 0.0f) ? 0 : (ushort)(0x3F80u | ((__float_as_uint(v.y) >> 16) & 0x8000u));
        o.z = (v.z == 0.0f) ? 0 : (ushort)(0x3F80u | ((__float_as_uint(v.z) >> 16) & 0x8000u));
        o.w = (v.w == 0.0f) ? 0 : (ushort)(0x3F80u | ((__float_as_uint(v.w) >> 16) & 0x8000u));
        *reinterpret_cast<ushort4*>(&dst[(size_t)i * 4]) = o;
    }

    #pragma unroll
    for (int o = 32; o > 0; o >>= 1) s += __shfl_xor(s, o);
    __shared__ float red[4];
    const int wid = threadIdx.x >> 6, lane = threadIdx.x & 63;
    if (lane == 0) red[wid] = s;
    __syncthreads();
    if (threadIdx.x == 0)
        atomicAdd(&scales[which], red[0] + red[1] + red[2] + red[3]);
}

// ---------------------------------------------------------------------------
// prep_inputs: x -> bf16 into combined[:,0:2048] and combined2[:,0:2048];
//              hidden -> bf16 into combined[:,2048:4096]
// ---------------------------------------------------------------------------
__global__ __launch_bounds__(256) void prep_inputs(
    const float* __restrict__ x, const float* __restrict__ hidden,
    __hip_bfloat16* __restrict__ combined, __hip_bfloat16* __restrict__ combined2)
{
    const int which = blockIdx.y;
    const float* src = which ? hidden : x;
    const int total4 = BB * II / 4;
    const int tid = blockIdx.x * 256 + threadIdx.x;
    const int stride = gridDim.x * 256;

    for (int i = tid; i < total4; i += stride) {
        float4 v = reinterpret_cast<const float4*>(src)[i];
        int e = i * 4;
        int row = e >> 11;
        int col = e & 2047;
        union { ushort4 u; __hip_bfloat16 h[4]; } o;
        o.h[0] = __float2bfloat16(v.x);
        o.h[1] = __float2bfloat16(v.y);
        o.h[2] = __float2bfloat16(v.z);
        o.h[3] = __float2bfloat16(v.w);
        size_t off = (size_t)row * KK + (which ? 2048 + col : col);
        *reinterpret_cast<ushort4*>(&combined[off]) = o.u;
        if (!which)
            *reinterpret_cast<ushort4*>(&combined2[off]) = o.u;
    }
}

// ---------------------------------------------------------------------------
// m201-style 8-phase GEMM: C = A[M,K] @ W[N,K]^T, binarized epilogues.
// BM x 256 tile, BK=64, 512 threads (8 waves, 2M x 4N), per-wave BM/2 x 64 C.
// Iteration = 2 K-tiles (E=buf0, O=buf1), 8 phases. One half-tile staged per
// phase into the buffer slot freed by liveness (B frags are register-cached,
// so B slots free after their first phase). Counted waits ONLY at P0/P4:
//   P0: vmcnt(4)        (keeps B(O) halves in flight)
//   P4: vmcnt(4+LA)     (keeps B(E+2) + A(E+2)h0)
// New-tile fragment reads happen AFTER the P0/P4 barrier (cross-wave staging
// is only guaranteed visible after drain + barrier).
// LDS swizzle byte ^= (row&7)<<4 via pre-swizzled global source (rule #21).
// ---------------------------------------------------------------------------
#define RD_A(ab, m0)                                                           \
    _Pragma("unroll") for (int mm = 0; mm < MPP; mm++)                         \
    _Pragma("unroll") for (int k = 0; k < 2; k++)                              \
        afr[mm][k] = *(const bf16x8*)((ab) + arowb[(m0) + mm] + colb[k]);

#define RD_B(bb)                                                               \
    _Pragma("unroll") for (int n = 0; n < 4; n++)                              \
    _Pragma("unroll") for (int k = 0; k < 2; k++)                              \
        bfrag[n][k] = *(const bf16x8*)((bb) + browb[n] + colb[k]);

#define DO_MFMA(m0)                                                            \
    _Pragma("unroll") for (int mm = 0; mm < MPP; mm++)                         \
    _Pragma("unroll") for (int n = 0; n < 4; n++)                              \
    _Pragma("unroll") for (int k = 0; k < 2; k++)                              \
        acc[(m0) + mm][n] = __builtin_amdgcn_mfma_f32_16x16x32_bf16(           \
            afr[mm][k], bfrag[n][k], acc[(m0) + mm][n], 0, 0, 0);

#define PHASE_MID(ab, m0, STAGE)                                               \
    RD_A(ab, m0);                                                              \
    STAGE;                                                                     \
    __builtin_amdgcn_s_barrier();                                              \
    asm volatile("s_waitcnt lgkmcnt(0)" ::: "memory");                         \
    __builtin_amdgcn_s_setprio(1);                                             \
    DO_MFMA(m0);                                                               \
    __builtin_amdgcn_s_setprio(0);                                             \
    __builtin_amdgcn_s_barrier();

template <int EPI, int BM>
__global__ __launch_bounds__(512, 2) void gemm8p(
    const __hip_bfloat16* __restrict__ A,    // [4096][4096] bf16
    const __hip_bfloat16* __restrict__ Bw,   // [N][4096] bf16 (signs)
    const float* __restrict__ scales,
    const float* __restrict__ b_r, const float* __restrict__ b_z,
    const float* __restrict__ b_n,
    const float* __restrict__ hidden,        // [4096][2048] f32
    float* __restrict__ z_buf,               // [4096][2048] f32
    __hip_bfloat16* __restrict__ combined2,  // [4096][4096] bf16
    float* __restrict__ out)                 // [4096][2048] f32
{
    constexpr int MF    = BM / 32;     // m-fragments per wave (8 / 4)
    constexpr int MPP   = MF / 4;      // m per phase (2 / 1)
    constexpr int WRS   = BM / 2;      // wave row stride
    constexpr int AH    = BM * 64;     // A half-tile bytes (16K / 8K)
    constexpr int ATILE = BM * 128;    // A tile bytes (32K / 16K)
    constexpr int BOFF  = 2 * ATILE;   // B region offset
    constexpr int LA    = BM / 128;    // load_lds16 calls per A half (2 / 1)

    __shared__ __align__(16) char smem[2 * ATILE + 65536];

    const int T = threadIdx.x;
    const int lane = T & 63;
    const int wid = T >> 6;
    const int wr = wid >> 2;    // 0..1
    const int wc = wid & 3;     // 0..3

    // bijective XCD swizzle (nwg = 256 for both grids)
    const int nbn = gridDim.x;
    const int nwg = nbn * gridDim.y;
    const int bid = blockIdx.y * nbn + blockIdx.x;
    const int swz = (bid & 7) * (nwg >> 3) + (bid >> 3);
    const int bn = swz % nbn;
    const int bm = swz / nbn;

    // fragment read byte-offsets (swizzled)
    int arowb[MF], browb[4], colb[2];
    #pragma unroll
    for (int m = 0; m < MF; m++) arowb[m] = (wr * WRS + m * 16 + (lane & 15)) << 7;
    #pragma unroll
    for (int n = 0; n < 4; n++) browb[n] = (wc * 64 + n * 16 + (lane & 15)) << 7;
    #pragma unroll
    for (int k = 0; k < 2; k++)
        colb[k] = (k * 64 + ((lane >> 4) << 4)) ^ ((lane & 7) << 4);

    // staging: thread T covers row (T>>3), source col pre-inverse-swizzled
    const int srow = T >> 3;                       // 0..63
    const int scol = ((T & 7) ^ (srow & 7)) << 3;  // element offset
    const __hip_bfloat16* gA = A  + (size_t)(bm * BM  + srow) * KK + scol;
    const __hip_bfloat16* gB = Bw + (size_t)(bn * 256 + srow) * KK + scol;

    auto stA = [&](int tile, int h) {
        const __hip_bfloat16* g = gA + (size_t)(h * WRS) * KK + ((tile & 63) << 6);
        char* l = smem + (tile & 1) * ATILE + h * AH + T * 16;
        load_lds16(g, l);
        if constexpr (LA == 2) load_lds16(g + (size_t)64 * KK, l + 8192);
    };
    auto stB = [&](int tile, int h) {
        const __hip_bfloat16* g = gB + (size_t)(h * 128) * KK + ((tile & 63) << 6);
        char* l = smem + BOFF + (tile & 1) * 32768 + h * 16384 + T * 16;
        load_lds16(g, l);
        load_lds16(g + (size_t)64 * KK, l + 8192);
    };

    f32x4 acc[MF][4] = {};

    // prologue: B(0), A(0), B(1)  (order matters for P0's vmcnt(4))
    stB(0, 0); stB(0, 1); stA(0, 0); stA(0, 1); stB(1, 0); stB(1, 1);

    const char* ab0 = smem;
    const char* ab1 = smem + ATILE;
    const char* bb0 = smem + BOFF;
    const char* bb1 = smem + BOFF + 32768;

    for (int t = 0; t < NITER; ++t) {
        const int O = 2 * t + 1;
        const int E2 = 2 * t + 2;
        const int O2 = 2 * t + 3;

        bf16x8 bfrag[4][2];
        bf16x8 afr[MPP][2];

        // ---- P0: drain E-tile loads (keep B(O)); reads AFTER barrier
        asm volatile("s_waitcnt vmcnt(4)" ::: "memory");
        __builtin_amdgcn_s_barrier();
        __builtin_amdgcn_sched_barrier(0);
        RD_B(bb0);
        RD_A(ab0, 0);
        stA(O, 0);
        asm volatile("s_waitcnt lgkmcnt(0)" ::: "memory");
        __builtin_amdgcn_s_setprio(1);
        DO_MFMA(0);
        __builtin_amdgcn_s_setprio(0);
        __builtin_amdgcn_s_barrier();

        // ---- P1..P3 on tile E
        PHASE_MID(ab0, 1 * MPP, stA(O, 1));
        PHASE_MID(ab0, 2 * MPP, stB(E2, 0));
        PHASE_MID(ab0, 3 * MPP, stB(E2, 1));

        // ---- P4: stage A(E+2)h0, drain O-tile loads (keep B(E+2)+A(E+2)h0)
        stA(E2, 0);
        if constexpr (LA == 2)
            asm volatile("s_waitcnt vmcnt(6)" ::: "memory");
        else
            asm volatile("s_waitcnt vmcnt(5)" ::: "memory");
        __builtin_amdgcn_s_barrier();
        __builtin_amdgcn_sched_barrier(0);
        RD_B(bb1);
        RD_A(ab1, 0);
        asm volatile("s_waitcnt lgkmcnt(0)" ::: "memory");
        __builtin_amdgcn_s_setprio(1);
        DO_MFMA(0);
        __builtin_amdgcn_s_setprio(0);
        __builtin_amdgcn_s_barrier();

        // ---- P5..P7 on tile O
        PHASE_MID(ab1, 1 * MPP, stA(E2, 1));
        PHASE_MID(ab1, 2 * MPP, stB(O2, 0));
        PHASE_MID(ab1, 3 * MPP, stB(O2, 1));
    }

    asm volatile("s_waitcnt vmcnt(0)" ::: "memory");
    __builtin_amdgcn_sched_barrier(0);

    // ---- epilogue
    const float inv_cnt = 1.0f / ((float)HH * (float)KK);

    if (EPI == 1) {
        const bool is_r = (bn < 8);
        const float scale = (is_r ? scales[0] : scales[1]) * inv_cnt;
        const float* bias = is_r ? b_r : b_z;
        #pragma unroll
        for (int m = 0; m < MF; m++) {
            #pragma unroll
            for (int n = 0; n < 4; n++) {
                const int col = bn * 256 + wc * 64 + n * 16 + (lane & 15);
                const int j = is_r ? col : col - 2048;
                const float bj = bias[j];
                #pragma unroll
                for (int i = 0; i < 4; i++) {
                    const int row = bm * BM + wr * WRS + m * 16 + ((lane >> 4) << 2) + i;
                    float pre = acc[m][n][i] * scale + bj;
                    float sg = 1.0f / (1.0f + __expf(-pre));
                    if (is_r) {
                        float rh = sg * hidden[(size_t)row * HH + j];
                        combined2[(size_t)row * KK + 2048 + j] = __float2bfloat16(rh);
                    } else {
                        z_buf[(size_t)row * HH + j] = sg;
                    }
                }
            }
        }
    } else {
        const float scale = scales[2] * inv_cnt;
        #pragma unroll
        for (int m = 0; m < MF; m++) {
            #pragma unroll
            for (int n = 0; n < 4; n++) {
                const int col = bn * 256 + wc * 64 + n * 16 + (lane & 15);
                const float bj = b_n[col];
                #pragma unroll
                for (int i = 0; i < 4; i++) {
                    const int row = bm * BM + wr * WRS + m * 16 + ((lane >> 4) << 2) + i;
                    float pre = acc[m][n][i] * scale + bj;
                    float nn = tanhf(pre);
                    size_t o = (size_t)row * HH + col;
                    float z = z_buf[o];
                    float h = hidden[o];
                    out[o] = (1.0f - z) * h + z * nn;
                }
            }
        }
    }
}

// ---------------------------------------------------------------------------
extern "C" void kernel_launch(void* const* d_in, const int* in_sizes, int n_in,
                              void* d_out, int out_size, void* d_ws, size_t ws_size,
                              hipStream_t stream) {
    const float* x      = (const float*)d_in[0];
    const float* hidden = (const float*)d_in[1];
    const float* w_r    = (const float*)d_in[2];
    const float* b_r    = (const float*)d_in[3];
    const float* w_z    = (const float*)d_in[4];
    const float* b_z    = (const float*)d_in[5];
    const float* w_n    = (const float*)d_in[6];
    const float* b_n    = (const float*)d_in[7];
    float* out = (float*)d_out;

    char* ws = (char*)d_ws;
    size_t off = 0;
    float* scales = (float*)(ws + off);                 off += 256;
    __hip_bfloat16* combined  = (__hip_bfloat16*)(ws + off); off += (size_t)BB * KK * 2;
    __hip_bfloat16* combined2 = (__hip_bfloat16*)(ws + off); off += (size_t)BB * KK * 2;
    __hip_bfloat16* sign_rz   = (__hip_bfloat16*)(ws + off); off += (size_t)2 * HH * KK * 2;
    __hip_bfloat16* sign_n    = (__hip_bfloat16*)(ws + off); off += (size_t)HH * KK * 2;
    float* z_buf = (float*)(ws + off);                  off += (size_t)BB * HH * 4;

    hipMemsetAsync(scales, 0, 3 * sizeof(float), stream);

    prep_weights<<<dim3(512, 3), 256, 0, stream>>>(w_r, w_z, w_n,
                                                   sign_rz, sign_n, scales);
    prep_inputs<<<dim3(1024, 2), 256, 0, stream>>>(x, hidden, combined, combined2);

    // GEMM1: r||z  (N = 4096), 256x256 tiles, 256 blocks = 1/CU
    gemm8p<1, 256><<<dim3(16, 16), 512, 0, stream>>>(combined, sign_rz, scales,
                                                     b_r, b_z, b_n, hidden,
                                                     z_buf, combined2, out);
    // GEMM2: n  (N = 2048), 128x256 tiles, 256 blocks = 1/CU
    gemm8p<2, 128><<<dim3(8, 32), 512, 0, stream>>>(combined2, sign_n, scales,
                                                    b_r, b_z, b_n, hidden,
                                                    z_buf, combined2, out);
}